// Round 9
// baseline (18.929 us; speedup 1.0000x reference)
//
#include <hip/hip_runtime.h>
#include <hip/hip_bf16.h>

#define NGRID  2048
#define BATCH  4
#define CIN    16
#define COUT   32
#define NOUT   1024
#define NT     16                     // targets per block
#define NW     16                     // waves per block = K slices
#define KSL    (NGRID / NW)           // 128 grid points per wave
#define KSTEP  (KSL / 32)             // 4 MFMA K-steps per wave
#define NBLK   (BATCH * (NOUT / NT))  // 256 blocks

typedef short bf16x8 __attribute__((ext_vector_type(8)));
typedef float f32x4  __attribute__((ext_vector_type(4)));

__device__ __forceinline__ float fexp2(float x) {
#if __has_builtin(__builtin_amdgcn_exp2f)
    return __builtin_amdgcn_exp2f(x);
#else
    return exp2f(x);
#endif
}

union ABfrag { bf16x8 v; short2 s2[4]; };

__device__ __forceinline__ short2 pk_bf16(float lo, float hi) {
    __hip_bfloat162 h = __float22bfloat162_rn(float2{lo, hi});
    short2 r;
    __builtin_memcpy(&r, &h, 4);
    return r;
}

// EXACT R5 kernel (best: 11.94 us single-launch). This round: launched twice
// as a decomposition probe (K vs fixed overhead F for THIS graph shape).
__global__ __launch_bounds__(1024) void conv_decoder_mfma(
        const float* __restrict__ r,      // (B, CIN, NGRID)
        const float* __restrict__ xc,     // (B*NCTX) = 1024 floats
        const float* __restrict__ xt,     // (B*NOUT) = 4096 floats
        const float* __restrict__ sigma,  // (CIN)
        const float* __restrict__ W,      // (CIN, COUT)
        const float* __restrict__ bias,   // (COUT)
        float* __restrict__ out) {        // (B, NOUT, COUT)
    const int tid  = threadIdx.x;
    const int lane = tid & 63;
    const int wv   = tid >> 6;            // 0..15 = K slice
    const int blk  = blockIdx.x;
    const int b    = blk >> 6;            // 64 target-groups per batch
    const int tg0  = (blk & 63) * NT;

    __shared__ float part[NW][CIN][NT];   // 16 KB
    __shared__ float zbuf[CIN][NT];       // 1 KB
    __shared__ float smn[NW], smx[NW];

    // ---- block-wide min/max over xc (1024) + xt (4096) ----
    float mn, mx;
    {
        float v = xc[tid];
        mn = v; mx = v;
        float4 u = *reinterpret_cast<const float4*>(xt + tid * 4);
        mn = fminf(mn, fminf(fminf(u.x, u.y), fminf(u.z, u.w)));
        mx = fmaxf(mx, fmaxf(fmaxf(u.x, u.y), fmaxf(u.z, u.w)));
        #pragma unroll
        for (int off = 32; off; off >>= 1) {
            mn = fminf(mn, __shfl_xor(mn, off));
            mx = fmaxf(mx, __shfl_xor(mx, off));
        }
    }
    if (lane == 0) { smn[wv] = mn; smx[wv] = mx; }
    __syncthreads();
    #pragma unroll
    for (int w2 = 0; w2 < NW; ++w2) {
        mn = fminf(mn, smn[w2]);
        mx = fmaxf(mx, smx[w2]);
    }
    const float xmin = mn - 0.1f;
    const float step = ((mx + 0.1f) - xmin) * (1.0f / (float)(NGRID - 1));

    // ---- per-channel exponent coefficients; uniformity check ----
    const float LOG2E = 1.4426950408889634f;
    float a2[CIN];
    #pragma unroll
    for (int c = 0; c < CIN; ++c)
        a2[c] = -0.5f * LOG2E * fexp2(-2.0f * LOG2E * sigma[c]);  // exp2(a2*d^2)
    bool uni = true;
    #pragma unroll
    for (int c = 1; c < CIN; ++c) uni = uni && (a2[c] == a2[0]);

    const int t  = lane & 15;             // target col (B/C) ; also channel row for A
    const int kb = lane >> 4;             // k-group
    const int wk0 = wv * KSL;
    const float xT = xt[b * NOUT + tg0 + t];
    const float* rb = r + (size_t)b * (CIN * NGRID);

    f32x4 acc = {0.0f, 0.0f, 0.0f, 0.0f};

    if (uni) {
        const float s     = sqrtf(-a2[0]);   // w = exp2(-(s*g - s*x)^2)
        const float sxm   = s * xmin;
        const float sstep = s * step;
        const float sx    = s * xT;
        const float* rrow = rb + (lane & 15) * NGRID + wk0 + kb * 8;

        #pragma unroll
        for (int kk = 0; kk < KSTEP; ++kk) {
            const int k0 = wk0 + kk * 32;
            float4 r0 = *reinterpret_cast<const float4*>(rrow + kk * 32);
            float4 r1 = *reinterpret_cast<const float4*>(rrow + kk * 32 + 4);
            ABfrag A;
            A.s2[0] = pk_bf16(r0.x, r0.y);
            A.s2[1] = pk_bf16(r0.z, r0.w);
            A.s2[2] = pk_bf16(r1.x, r1.y);
            A.s2[3] = pk_bf16(r1.z, r1.w);
            float wgt[8];
            #pragma unroll
            for (int j = 0; j < 8; ++j) {
                float gi = (float)(k0 + kb * 8 + j);
                float d  = __builtin_fmaf(sstep, gi, sxm) - sx;
                wgt[j] = fexp2(-(d * d));
            }
            ABfrag Bf;
            #pragma unroll
            for (int p = 0; p < 4; ++p)
                Bf.s2[p] = pk_bf16(wgt[2 * p], wgt[2 * p + 1]);
            acc = __builtin_amdgcn_mfma_f32_16x16x32_bf16(A.v, Bf.v, acc, 0, 0, 0);
        }
    } else {
        // generic per-channel-sigma fallback (f32 VALU), same C-frag layout
        #pragma unroll 1
        for (int k = 0; k < KSL; ++k) {
            float g  = xmin + step * (float)(wk0 + k);
            float d  = g - xT;
            float d2 = d * d;
            #pragma unroll
            for (int reg = 0; reg < 4; ++reg) {
                int c = kb * 4 + reg;
                acc[reg] += rb[c * NGRID + wk0 + k] * fexp2(a2[c] * d2);
            }
        }
    }

    // ---- write C fragments; cross-wave K reduction ----
    #pragma unroll
    for (int reg = 0; reg < 4; ++reg)
        part[wv][kb * 4 + reg][t] = acc[reg];
    __syncthreads();

    if (tid < CIN * NT) {                 // 256 threads: one (c,t) each
        const int c  = tid >> 4;
        const int tt = tid & 15;
        float z = 0.0f;
        #pragma unroll
        for (int w2 = 0; w2 < NW; ++w2) z += part[w2][c][tt];
        zbuf[c][tt] = z;
    }
    __syncthreads();

    // ---- epilogue: 512 threads, one (t, cout) each ----
    if (tid < NT * COUT) {
        const int tt = tid >> 5;
        const int co = tid & 31;
        float o = bias[co];
        #pragma unroll
        for (int c = 0; c < CIN; ++c)
            o = __builtin_fmaf(zbuf[c][tt], W[c * COUT + co], o);
        out[((size_t)b * NOUT + tg0 + tt) * COUT + co] = o;
    }
}

extern "C" void kernel_launch(void* const* d_in, const int* in_sizes, int n_in,
                              void* d_out, int out_size, void* d_ws, size_t ws_size,
                              hipStream_t stream) {
    const float* r  = (const float*)d_in[0];  // (4,16,2048)
    const float* xc = (const float*)d_in[1];  // (4,256,1)
    // d_in[2] = y_context — unused by the reference
    const float* xt = (const float*)d_in[3];  // (4,1024,1)
    const float* sg = (const float*)d_in[4];  // (16)
    const float* W  = (const float*)d_in[5];  // (16,32)
    const float* bs = (const float*)d_in[6];  // (32)
    float* out = (float*)d_out;               // (4,1024,32) f32

    // PROBE: double-launch of the best (R5) kernel to decompose dur = F + K.
    // R5 single-launch = 11.94 us. Delta of this bench vs 11.94 = K + node gap.
    // Deterministic: second launch rewrites identical values.
    conv_decoder_mfma<<<NBLK, 1024, 0, stream>>>(r, xc, xt, sg, W, bs, out);
    conv_decoder_mfma<<<NBLK, 1024, 0, stream>>>(r, xc, xt, sg, W, bs, out);
}

// Round 10
// 15.587 us; speedup vs baseline: 1.2144x; 1.2144x over previous
//
#include <hip/hip_runtime.h>
#include <hip/hip_bf16.h>

#define NGRID  2048
#define BATCH  4
#define CIN    16
#define COUT   32
#define NOUT   1024
#define NT     16                     // targets per block
#define NW     16                     // waves per block = K slices
#define KSL    (NGRID / NW)           // 128 grid points per wave
#define KSTEP  (KSL / 32)             // 4 MFMA K-steps per wave
#define NBLK   (BATCH * (NOUT / NT))  // 256 blocks

typedef short bf16x8 __attribute__((ext_vector_type(8)));
typedef float f32x4  __attribute__((ext_vector_type(4)));

__device__ __forceinline__ float fexp2(float x) {
#if __has_builtin(__builtin_amdgcn_exp2f)
    return __builtin_amdgcn_exp2f(x);
#else
    return exp2f(x);
#endif
}

union ABfrag { bf16x8 v; short2 s2[4]; };

__device__ __forceinline__ short2 pk_bf16(float lo, float hi) {
    __hip_bfloat162 h = __float22bfloat162_rn(float2{lo, hi});
    short2 r;
    __builtin_memcpy(&r, &h, 4);
    return r;
}

// ws layout: [0]=xmin, [1]=step, [2]=s(uniform), [3]=uni flag, [4..19]=a2[c]

// Kernel 1 (1 block x 256 threads): global min/max over xc+xt, sigma processing.
__global__ __launch_bounds__(256) void prep_kernel(
        const float* __restrict__ xc,     // 1024 floats
        const float* __restrict__ xt,     // 4096 floats
        const float* __restrict__ sigma,  // 16
        float* __restrict__ ws) {
    const int tid  = threadIdx.x;
    const int lane = tid & 63;
    const int wv   = tid >> 6;

    float4 v = *reinterpret_cast<const float4*>(xc + tid * 4);
    float mn = fminf(fminf(v.x, v.y), fminf(v.z, v.w));
    float mx = fmaxf(fmaxf(v.x, v.y), fmaxf(v.z, v.w));
    #pragma unroll
    for (int k = 0; k < 4; ++k) {
        float4 u = *reinterpret_cast<const float4*>(xt + (k * 256 + tid) * 4);
        mn = fminf(mn, fminf(fminf(u.x, u.y), fminf(u.z, u.w)));
        mx = fmaxf(mx, fmaxf(fmaxf(u.x, u.y), fmaxf(u.z, u.w)));
    }
    #pragma unroll
    for (int off = 32; off; off >>= 1) {
        mn = fminf(mn, __shfl_xor(mn, off));
        mx = fmaxf(mx, __shfl_xor(mx, off));
    }
    __shared__ float smn[4], smx[4];
    if (lane == 0) { smn[wv] = mn; smx[wv] = mx; }
    __syncthreads();
    if (wv == 0) {
        mn = fminf(fminf(smn[0], smn[1]), fminf(smn[2], smn[3]));
        mx = fmaxf(fmaxf(smx[0], smx[1]), fmaxf(smx[2], smx[3]));
        const float xmin = mn - 0.1f;
        const float step = ((mx + 0.1f) - xmin) * (1.0f / (float)(NGRID - 1));

        const float LOG2E = 1.4426950408889634f;
        const int c = lane & 15;
        float a2c = -0.5f * LOG2E * fexp2(-2.0f * LOG2E * sigma[c]);
        if (lane < CIN) ws[4 + c] = a2c;
        float a20 = __shfl(a2c, 0);
        bool ok = (lane < CIN) ? (a2c == a20) : true;
        bool uni = __all(ok);
        if (lane == 0) {
            ws[0] = xmin;
            ws[1] = step;
            ws[2] = sqrtf(-a20);   // w = exp2(-(s*g - s*x)^2)
            ws[3] = uni ? 1.0f : 0.0f;
        }
    }
}

// Kernel 2: block = (batch, 16 targets), 16 waves; wave wv owns K-slice [wv*128, +128).
// z = r_bf16 @ w_bf16 via mfma_f32_16x16x32_bf16; no block-wide dependency before
// the main compute (minmax/sigma precomputed in ws) -> launch skew hides under work.
//   A: row c = lane&15, k = (lane>>4)*8 + j ; B: col t = lane&15, same k
//   C/D (m89-verified): col t = lane&15, row c = (lane>>4)*4 + reg
__global__ __launch_bounds__(1024) void conv_decoder_mfma(
        const float* __restrict__ r,      // (B, CIN, NGRID)
        const float* __restrict__ xt,     // (B*NOUT)
        const float* __restrict__ ws,     // prep results
        const float* __restrict__ W,      // (CIN, COUT)
        const float* __restrict__ bias,   // (COUT)
        float* __restrict__ out) {        // (B, NOUT, COUT)
    const int tid  = threadIdx.x;
    const int lane = tid & 63;
    const int wv   = tid >> 6;            // 0..15 = K slice
    const int blk  = blockIdx.x;
    const int b    = blk >> 6;            // 64 target-groups per batch
    const int tg0  = (blk & 63) * NT;

    __shared__ float part[NW][CIN][NT];   // 16 KB
    __shared__ float zbuf[CIN][NT];       // 1 KB

    const float xmin = ws[0];
    const float step = ws[1];
    const float s    = ws[2];
    const bool  uni  = ws[3] != 0.0f;

    const int t   = lane & 15;            // target col (B/C); channel row for A
    const int kb  = lane >> 4;            // k-group
    const int wk0 = wv * KSL;
    const float xT = xt[b * NOUT + tg0 + t];
    const float* rb = r + (size_t)b * (CIN * NGRID);

    f32x4 acc = {0.0f, 0.0f, 0.0f, 0.0f};

    if (uni) {
        const float sxm   = s * xmin;
        const float sstep = s * step;
        const float sx    = s * xT;
        const float* rrow = rb + t * NGRID + wk0 + kb * 8;

        #pragma unroll
        for (int kk = 0; kk < KSTEP; ++kk) {
            const int k0 = wk0 + kk * 32;
            float4 r0 = *reinterpret_cast<const float4*>(rrow + kk * 32);
            float4 r1 = *reinterpret_cast<const float4*>(rrow + kk * 32 + 4);
            ABfrag A;
            A.s2[0] = pk_bf16(r0.x, r0.y);
            A.s2[1] = pk_bf16(r0.z, r0.w);
            A.s2[2] = pk_bf16(r1.x, r1.y);
            A.s2[3] = pk_bf16(r1.z, r1.w);
            float wgt[8];
            #pragma unroll
            for (int j = 0; j < 8; ++j) {
                float gi = (float)(k0 + kb * 8 + j);
                float d  = __builtin_fmaf(sstep, gi, sxm) - sx;
                wgt[j] = fexp2(-(d * d));
            }
            ABfrag Bf;
            #pragma unroll
            for (int p = 0; p < 4; ++p)
                Bf.s2[p] = pk_bf16(wgt[2 * p], wgt[2 * p + 1]);
            acc = __builtin_amdgcn_mfma_f32_16x16x32_bf16(A.v, Bf.v, acc, 0, 0, 0);
        }
    } else {
        // generic per-channel-sigma fallback (f32 VALU), same C-frag layout
        #pragma unroll 1
        for (int k = 0; k < KSL; ++k) {
            float g  = xmin + step * (float)(wk0 + k);
            float d  = g - xT;
            float d2 = d * d;
            #pragma unroll
            for (int reg = 0; reg < 4; ++reg) {
                int c = kb * 4 + reg;
                acc[reg] += rb[c * NGRID + wk0 + k] * fexp2(ws[4 + c] * d2);
            }
        }
    }

    // ---- write C fragments; cross-wave K reduction ----
    #pragma unroll
    for (int reg = 0; reg < 4; ++reg)
        part[wv][kb * 4 + reg][t] = acc[reg];
    __syncthreads();

    if (tid < CIN * NT) {                 // 256 threads: one (c,t) each
        const int c  = tid >> 4;
        const int tt = tid & 15;
        float z = 0.0f;
        #pragma unroll
        for (int w2 = 0; w2 < NW; ++w2) z += part[w2][c][tt];
        zbuf[c][tt] = z;
    }
    __syncthreads();

    // ---- epilogue: 512 threads, one (t, cout) each ----
    if (tid < NT * COUT) {
        const int tt = tid >> 5;
        const int co = tid & 31;
        float o = bias[co];
        #pragma unroll
        for (int c = 0; c < CIN; ++c)
            o = __builtin_fmaf(zbuf[c][tt], W[c * COUT + co], o);
        out[((size_t)b * NOUT + tg0 + tt) * COUT + co] = o;
    }
}

extern "C" void kernel_launch(void* const* d_in, const int* in_sizes, int n_in,
                              void* d_out, int out_size, void* d_ws, size_t ws_size,
                              hipStream_t stream) {
    const float* r  = (const float*)d_in[0];  // (4,16,2048)
    const float* xc = (const float*)d_in[1];  // (4,256,1)
    // d_in[2] = y_context — unused by the reference
    const float* xt = (const float*)d_in[3];  // (4,1024,1)
    const float* sg = (const float*)d_in[4];  // (16)
    const float* W  = (const float*)d_in[5];  // (16,32)
    const float* bs = (const float*)d_in[6];  // (32)
    float* out = (float*)d_out;               // (4,1024,32) f32
    float* ws  = (float*)d_ws;

    prep_kernel<<<1, 256, 0, stream>>>(xc, xt, sg, ws);
    conv_decoder_mfma<<<NBLK, 1024, 0, stream>>>(r, xt, ws, W, bs, out);
}

// Round 11
// 14.520 us; speedup vs baseline: 1.3036x; 1.0735x over previous
//
#include <hip/hip_runtime.h>
#include <hip/hip_bf16.h>

#define NGRID  2048
#define BATCH  4
#define CIN    16
#define COUT   32
#define NOUT   1024
#define NT     16                     // targets per block
#define NW     16                     // waves per block = K slices
#define KSL    (NGRID / NW)           // 128 grid points per wave
#define KSTEP  (KSL / 32)             // 4 MFMA K-steps per wave
#define NBLK   (BATCH * (NOUT / NT))  // 256 blocks

typedef short bf16x8 __attribute__((ext_vector_type(8)));
typedef float f32x4  __attribute__((ext_vector_type(4)));

__device__ __forceinline__ float fexp2(float x) {
#if __has_builtin(__builtin_amdgcn_exp2f)
    return __builtin_amdgcn_exp2f(x);
#else
    return exp2f(x);
#endif
}

union ABfrag { bf16x8 v; short2 s2[4]; };

__device__ __forceinline__ short2 pk_bf16(float lo, float hi) {
    __hip_bfloat162 h = __float22bfloat162_rn(float2{lo, hi});
    short2 r;
    __builtin_memcpy(&r, &h, 4);
    return r;
}

// R5 structure with ONE change: the block-wide minmax (loads+butterfly+LDS+barrier+
// scan-16) is replaced by a barrier-free PER-WAVE redundant minmax over all 5120
// x-floats (20 float4/lane, L1/L2-broadcast). No block-wide dependency before the
// MFMA main loop -> waves start compute independently.
__global__ __launch_bounds__(1024) void conv_decoder_mfma(
        const float* __restrict__ r,      // (B, CIN, NGRID)
        const float* __restrict__ xc,     // 1024 floats
        const float* __restrict__ xt,     // 4096 floats
        const float* __restrict__ sigma,  // (CIN)
        const float* __restrict__ W,      // (CIN, COUT)
        const float* __restrict__ bias,   // (COUT)
        float* __restrict__ out) {        // (B, NOUT, COUT)
    const int tid  = threadIdx.x;
    const int lane = tid & 63;
    const int wv   = tid >> 6;            // 0..15 = K slice
    const int blk  = blockIdx.x;
    const int b    = blk >> 6;            // 64 target-groups per batch
    const int tg0  = (blk & 63) * NT;

    __shared__ float part[NW][CIN][NT];   // 16 KB
    __shared__ float zbuf[CIN][NT];       // 1 KB

    // ---- per-wave redundant min/max over xc (1024) + xt (4096), no barrier ----
    float mn, mx;
    {
        float4 v = *reinterpret_cast<const float4*>(xc + lane * 4);
        mn = fminf(fminf(v.x, v.y), fminf(v.z, v.w));
        mx = fmaxf(fmaxf(v.x, v.y), fmaxf(v.z, v.w));
        #pragma unroll
        for (int k = 1; k < 4; ++k) {
            float4 u = *reinterpret_cast<const float4*>(xc + (k * 64 + lane) * 4);
            mn = fminf(mn, fminf(fminf(u.x, u.y), fminf(u.z, u.w)));
            mx = fmaxf(mx, fmaxf(fmaxf(u.x, u.y), fmaxf(u.z, u.w)));
        }
        #pragma unroll
        for (int k = 0; k < 16; ++k) {
            float4 u = *reinterpret_cast<const float4*>(xt + (k * 64 + lane) * 4);
            mn = fminf(mn, fminf(fminf(u.x, u.y), fminf(u.z, u.w)));
            mx = fmaxf(mx, fmaxf(fmaxf(u.x, u.y), fmaxf(u.z, u.w)));
        }
        #pragma unroll
        for (int off = 32; off; off >>= 1) {
            mn = fminf(mn, __shfl_xor(mn, off));
            mx = fmaxf(mx, __shfl_xor(mx, off));
        }
    }
    const float xmin = mn - 0.1f;
    const float step = ((mx + 0.1f) - xmin) * (1.0f / (float)(NGRID - 1));

    // ---- per-channel exponent coefficients; uniformity check ----
    const float LOG2E = 1.4426950408889634f;
    float a2[CIN];
    #pragma unroll
    for (int c = 0; c < CIN; ++c)
        a2[c] = -0.5f * LOG2E * fexp2(-2.0f * LOG2E * sigma[c]);  // exp2(a2*d^2)
    bool uni = true;
    #pragma unroll
    for (int c = 1; c < CIN; ++c) uni = uni && (a2[c] == a2[0]);

    const int t  = lane & 15;             // target col (B/C); channel row for A
    const int kb = lane >> 4;             // k-group
    const int wk0 = wv * KSL;
    const float xT = xt[b * NOUT + tg0 + t];
    const float* rb = r + (size_t)b * (CIN * NGRID);

    f32x4 acc = {0.0f, 0.0f, 0.0f, 0.0f};

    if (uni) {
        const float s     = sqrtf(-a2[0]);   // w = exp2(-(s*g - s*x)^2)
        const float sxm   = s * xmin;
        const float sstep = s * step;
        const float sx    = s * xT;
        const float* rrow = rb + t * NGRID + wk0 + kb * 8;

        #pragma unroll
        for (int kk = 0; kk < KSTEP; ++kk) {
            const int k0 = wk0 + kk * 32;
            float4 r0 = *reinterpret_cast<const float4*>(rrow + kk * 32);
            float4 r1 = *reinterpret_cast<const float4*>(rrow + kk * 32 + 4);
            ABfrag A;
            A.s2[0] = pk_bf16(r0.x, r0.y);
            A.s2[1] = pk_bf16(r0.z, r0.w);
            A.s2[2] = pk_bf16(r1.x, r1.y);
            A.s2[3] = pk_bf16(r1.z, r1.w);
            float wgt[8];
            #pragma unroll
            for (int j = 0; j < 8; ++j) {
                float gi = (float)(k0 + kb * 8 + j);
                float d  = __builtin_fmaf(sstep, gi, sxm) - sx;
                wgt[j] = fexp2(-(d * d));
            }
            ABfrag Bf;
            #pragma unroll
            for (int p = 0; p < 4; ++p)
                Bf.s2[p] = pk_bf16(wgt[2 * p], wgt[2 * p + 1]);
            acc = __builtin_amdgcn_mfma_f32_16x16x32_bf16(A.v, Bf.v, acc, 0, 0, 0);
        }
    } else {
        // generic per-channel-sigma fallback (f32 VALU), same C-frag layout
        #pragma unroll 1
        for (int k = 0; k < KSL; ++k) {
            float g  = xmin + step * (float)(wk0 + k);
            float d  = g - xT;
            float d2 = d * d;
            #pragma unroll
            for (int reg = 0; reg < 4; ++reg) {
                int c = kb * 4 + reg;
                acc[reg] += rb[c * NGRID + wk0 + k] * fexp2(a2[c] * d2);
            }
        }
    }

    // ---- write C fragments; cross-wave K reduction ----
    #pragma unroll
    for (int reg = 0; reg < 4; ++reg)
        part[wv][kb * 4 + reg][t] = acc[reg];
    __syncthreads();

    if (tid < CIN * NT) {                 // 256 threads: one (c,t) each
        const int c  = tid >> 4;
        const int tt = tid & 15;
        float z = 0.0f;
        #pragma unroll
        for (int w2 = 0; w2 < NW; ++w2) z += part[w2][c][tt];
        zbuf[c][tt] = z;
    }
    __syncthreads();

    // ---- epilogue: 512 threads, one (t, cout) each ----
    if (tid < NT * COUT) {
        const int tt = tid >> 5;
        const int co = tid & 31;
        float o = bias[co];
        #pragma unroll
        for (int c = 0; c < CIN; ++c)
            o = __builtin_fmaf(zbuf[c][tt], W[c * COUT + co], o);
        out[((size_t)b * NOUT + tg0 + tt) * COUT + co] = o;
    }
}

extern "C" void kernel_launch(void* const* d_in, const int* in_sizes, int n_in,
                              void* d_out, int out_size, void* d_ws, size_t ws_size,
                              hipStream_t stream) {
    const float* r  = (const float*)d_in[0];  // (4,16,2048)
    const float* xc = (const float*)d_in[1];  // (4,256,1)
    // d_in[2] = y_context — unused by the reference
    const float* xt = (const float*)d_in[3];  // (4,1024,1)
    const float* sg = (const float*)d_in[4];  // (16)
    const float* W  = (const float*)d_in[5];  // (16,32)
    const float* bs = (const float*)d_in[6];  // (32)
    float* out = (float*)d_out;               // (4,1024,32) f32

    conv_decoder_mfma<<<NBLK, 1024, 0, stream>>>(r, xc, xt, sg, W, bs, out);
}

// Round 12
// 13.401 us; speedup vs baseline: 1.4125x; 1.0835x over previous
//
#include <hip/hip_runtime.h>
#include <hip/hip_bf16.h>

#define NGRID  2048
#define BATCH  4
#define CIN    16
#define COUT   32
#define NOUT   1024
#define NT     16                     // targets per block
#define NW     16                     // waves per block = K slices
#define KSL    (NGRID / NW)           // 128 grid points per wave
#define KSTEP  (KSL / 32)             // 4 MFMA K-steps per wave
#define NBLK   (BATCH * (NOUT / NT))  // 256 blocks

typedef short bf16x8 __attribute__((ext_vector_type(8)));
typedef float f32x4  __attribute__((ext_vector_type(4)));

__device__ __forceinline__ float fexp2(float x) {
#if __has_builtin(__builtin_amdgcn_exp2f)
    return __builtin_amdgcn_exp2f(x);
#else
    return exp2f(x);
#endif
}

union ABfrag { bf16x8 v; short2 s2[4]; };

__device__ __forceinline__ short2 pk_bf16(float lo, float hi) {
    __hip_bfloat162 h = __float22bfloat162_rn(float2{lo, hi});
    short2 r;
    __builtin_memcpy(&r, &h, 4);
    return r;
}

// R5 structure (best: 11.94us) with two in-place micro-cuts:
//  1. uniformity check on RAW sigma (no 16-exp chain in prologue; uni path
//     needs exp(sigma[0]) only; fallback recomputes a2[] cold).
//  2. main-loop r-loads + xT issued AFTER minmax loads, BEFORE butterfly/barrier
//     (L2 latency hides under butterfly+barrier; minmax keeps VMEM priority).
__global__ __launch_bounds__(1024) void conv_decoder_mfma(
        const float* __restrict__ r,      // (B, CIN, NGRID)
        const float* __restrict__ xc,     // 1024 floats
        const float* __restrict__ xt,     // 4096 floats
        const float* __restrict__ sigma,  // (CIN)
        const float* __restrict__ W,      // (CIN, COUT)
        const float* __restrict__ bias,   // (COUT)
        float* __restrict__ out) {        // (B, NOUT, COUT)
    const int tid  = threadIdx.x;
    const int lane = tid & 63;
    const int wv   = tid >> 6;            // 0..15 = K slice
    const int blk  = blockIdx.x;
    const int b    = blk >> 6;            // 64 target-groups per batch
    const int tg0  = (blk & 63) * NT;

    __shared__ float part[NW][CIN][NT];   // 16 KB
    __shared__ float zbuf[CIN][NT];       // 1 KB
    __shared__ float smn[NW], smx[NW];

    const int t  = lane & 15;             // target col (B/C); channel row for A
    const int kb = lane >> 4;             // k-group
    const int wk0 = wv * KSL;
    const float* rb   = r + (size_t)b * (CIN * NGRID);
    const float* rrow = rb + t * NGRID + wk0 + kb * 8;

    // ---- minmax loads first (they gate the block-wide barrier) ----
    float v0 = xc[tid];
    float4 u0 = *reinterpret_cast<const float4*>(xt + tid * 4);

    // ---- then issue main-loop loads: latency hides under butterfly+barrier ----
    float4 r0[KSTEP], r1[KSTEP];
    #pragma unroll
    for (int kk = 0; kk < KSTEP; ++kk) {
        r0[kk] = *reinterpret_cast<const float4*>(rrow + kk * 32);
        r1[kk] = *reinterpret_cast<const float4*>(rrow + kk * 32 + 4);
    }
    const float xT = xt[b * NOUT + tg0 + t];

    // ---- block-wide min/max reduction ----
    float mn = fminf(v0, fminf(fminf(u0.x, u0.y), fminf(u0.z, u0.w)));
    float mx = fmaxf(v0, fmaxf(fmaxf(u0.x, u0.y), fmaxf(u0.z, u0.w)));
    #pragma unroll
    for (int off = 32; off; off >>= 1) {
        mn = fminf(mn, __shfl_xor(mn, off));
        mx = fmaxf(mx, __shfl_xor(mx, off));
    }
    if (lane == 0) { smn[wv] = mn; smx[wv] = mx; }

    // ---- uniformity check on RAW sigma while the barrier assembles ----
    const float sg0 = sigma[0];
    bool uni = true;
    #pragma unroll
    for (int c = 1; c < CIN; ++c) uni = uni && (sigma[c] == sg0);

    __syncthreads();
    #pragma unroll
    for (int w2 = 0; w2 < NW; ++w2) {
        mn = fminf(mn, smn[w2]);
        mx = fmaxf(mx, smx[w2]);
    }
    const float xmin = mn - 0.1f;
    const float step = ((mx + 0.1f) - xmin) * (1.0f / (float)(NGRID - 1));

    const float LOG2E = 1.4426950408889634f;
    f32x4 acc = {0.0f, 0.0f, 0.0f, 0.0f};

    if (uni) {
        // w = exp2(-(s*g - s*x)^2), s = sqrt(0.5*LOG2E)*exp2(-LOG2E*sg0)
        const float s     = 0.8493218002880191f * fexp2(-LOG2E * sg0);
        const float sxm   = s * xmin;
        const float sstep = s * step;
        const float sx    = s * xT;

        #pragma unroll
        for (int kk = 0; kk < KSTEP; ++kk) {
            const int k0 = wk0 + kk * 32;
            ABfrag A;
            A.s2[0] = pk_bf16(r0[kk].x, r0[kk].y);
            A.s2[1] = pk_bf16(r0[kk].z, r0[kk].w);
            A.s2[2] = pk_bf16(r1[kk].x, r1[kk].y);
            A.s2[3] = pk_bf16(r1[kk].z, r1[kk].w);
            float wgt[8];
            #pragma unroll
            for (int j = 0; j < 8; ++j) {
                float gi = (float)(k0 + kb * 8 + j);
                float d  = __builtin_fmaf(sstep, gi, sxm) - sx;
                wgt[j] = fexp2(-(d * d));
            }
            ABfrag Bf;
            #pragma unroll
            for (int p = 0; p < 4; ++p)
                Bf.s2[p] = pk_bf16(wgt[2 * p], wgt[2 * p + 1]);
            acc = __builtin_amdgcn_mfma_f32_16x16x32_bf16(A.v, Bf.v, acc, 0, 0, 0);
        }
    } else {
        // generic per-channel-sigma fallback (f32 VALU), same C-frag layout
        float a2[CIN];
        #pragma unroll
        for (int c = 0; c < CIN; ++c)
            a2[c] = -0.5f * LOG2E * fexp2(-2.0f * LOG2E * sigma[c]);
        #pragma unroll 1
        for (int k = 0; k < KSL; ++k) {
            float g  = xmin + step * (float)(wk0 + k);
            float d  = g - xT;
            float d2 = d * d;
            #pragma unroll
            for (int reg = 0; reg < 4; ++reg) {
                int c = kb * 4 + reg;
                acc[reg] += rb[c * NGRID + wk0 + k] * fexp2(a2[c] * d2);
            }
        }
    }

    // ---- write C fragments; cross-wave K reduction ----
    #pragma unroll
    for (int reg = 0; reg < 4; ++reg)
        part[wv][kb * 4 + reg][t] = acc[reg];
    __syncthreads();

    if (tid < CIN * NT) {                 // 256 threads: one (c,t) each
        const int c  = tid >> 4;
        const int tt = tid & 15;
        float z = 0.0f;
        #pragma unroll
        for (int w2 = 0; w2 < NW; ++w2) z += part[w2][c][tt];
        zbuf[c][tt] = z;
    }
    __syncthreads();

    // ---- epilogue: 512 threads, one (t, cout) each ----
    if (tid < NT * COUT) {
        const int tt = tid >> 5;
        const int co = tid & 31;
        float o = bias[co];
        #pragma unroll
        for (int c = 0; c < CIN; ++c)
            o = __builtin_fmaf(zbuf[c][tt], W[c * COUT + co], o);
        out[((size_t)b * NOUT + tg0 + tt) * COUT + co] = o;
    }
}

extern "C" void kernel_launch(void* const* d_in, const int* in_sizes, int n_in,
                              void* d_out, int out_size, void* d_ws, size_t ws_size,
                              hipStream_t stream) {
    const float* r  = (const float*)d_in[0];  // (4,16,2048)
    const float* xc = (const float*)d_in[1];  // (4,256,1)
    // d_in[2] = y_context — unused by the reference
    const float* xt = (const float*)d_in[3];  // (4,1024,1)
    const float* sg = (const float*)d_in[4];  // (16)
    const float* W  = (const float*)d_in[5];  // (16,32)
    const float* bs = (const float*)d_in[6];  // (32)
    float* out = (float*)d_out;               // (4,1024,32) f32

    conv_decoder_mfma<<<NBLK, 1024, 0, stream>>>(r, xc, xt, sg, W, bs, out);
}

// Round 13
// 11.800 us; speedup vs baseline: 1.6042x; 1.1357x over previous
//
#include <hip/hip_runtime.h>
#include <hip/hip_bf16.h>

#define NGRID  2048
#define BATCH  4
#define CIN    16
#define COUT   32
#define NOUT   1024
#define NT     16                     // targets per block
#define NW     16                     // waves per block = K slices
#define KSL    (NGRID / NW)           // 128 grid points per wave
#define KSTEP  (KSL / 32)             // 4 MFMA K-steps per wave
#define NBLK   (BATCH * (NOUT / NT))  // 256 blocks

typedef short bf16x8 __attribute__((ext_vector_type(8)));
typedef float f32x4  __attribute__((ext_vector_type(4)));

__device__ __forceinline__ float fexp2(float x) {
#if __has_builtin(__builtin_amdgcn_exp2f)
    return __builtin_amdgcn_exp2f(x);
#else
    return exp2f(x);
#endif
}

union ABfrag { bf16x8 v; short2 s2[4]; };

__device__ __forceinline__ short2 pk_bf16(float lo, float hi) {
    __hip_bfloat162 h = __float22bfloat162_rn(float2{lo, hi});
    short2 r;
    __builtin_memcpy(&r, &h, 4);
    return r;
}

// EXACT R5 kernel — best measured configuration (11.94 us single-launch).
// Survived 5 attack rounds (R6/R7/R9/R10/R11 all regressed):
//  - loads in-loop (hoisting them regresses: VMEM queue + VGPR pressure)
//  - block-wide barrier minmax (per-wave redundant minmax costs L1 BW)
//  - single kernel node (any extra graph node costs ~4 us)
//  - 256 blocks x 1024 threads (NT=8/512-block and 2-block/CU variants regress)
__global__ __launch_bounds__(1024) void conv_decoder_mfma(
        const float* __restrict__ r,      // (B, CIN, NGRID)
        const float* __restrict__ xc,     // 1024 floats
        const float* __restrict__ xt,     // 4096 floats
        const float* __restrict__ sigma,  // (CIN)
        const float* __restrict__ W,      // (CIN, COUT)
        const float* __restrict__ bias,   // (COUT)
        float* __restrict__ out) {        // (B, NOUT, COUT)
    const int tid  = threadIdx.x;
    const int lane = tid & 63;
    const int wv   = tid >> 6;            // 0..15 = K slice
    const int blk  = blockIdx.x;
    const int b    = blk >> 6;            // 64 target-groups per batch
    const int tg0  = (blk & 63) * NT;

    __shared__ float part[NW][CIN][NT];   // 16 KB
    __shared__ float zbuf[CIN][NT];       // 1 KB
    __shared__ float smn[NW], smx[NW];

    // ---- block-wide min/max over xc (1024) + xt (4096) ----
    float mn, mx;
    {
        float v = xc[tid];
        mn = v; mx = v;
        float4 u = *reinterpret_cast<const float4*>(xt + tid * 4);
        mn = fminf(mn, fminf(fminf(u.x, u.y), fminf(u.z, u.w)));
        mx = fmaxf(mx, fmaxf(fmaxf(u.x, u.y), fmaxf(u.z, u.w)));
        #pragma unroll
        for (int off = 32; off; off >>= 1) {
            mn = fminf(mn, __shfl_xor(mn, off));
            mx = fmaxf(mx, __shfl_xor(mx, off));
        }
    }
    if (lane == 0) { smn[wv] = mn; smx[wv] = mx; }
    __syncthreads();
    #pragma unroll
    for (int w2 = 0; w2 < NW; ++w2) {
        mn = fminf(mn, smn[w2]);
        mx = fmaxf(mx, smx[w2]);
    }
    const float xmin = mn - 0.1f;
    const float step = ((mx + 0.1f) - xmin) * (1.0f / (float)(NGRID - 1));

    // ---- per-channel exponent coefficients; uniformity check ----
    const float LOG2E = 1.4426950408889634f;
    float a2[CIN];
    #pragma unroll
    for (int c = 0; c < CIN; ++c)
        a2[c] = -0.5f * LOG2E * fexp2(-2.0f * LOG2E * sigma[c]);  // exp2(a2*d^2)
    bool uni = true;
    #pragma unroll
    for (int c = 1; c < CIN; ++c) uni = uni && (a2[c] == a2[0]);

    const int t  = lane & 15;             // target col (B/C) ; also channel row for A
    const int kb = lane >> 4;             // k-group
    const int wk0 = wv * KSL;
    const float xT = xt[b * NOUT + tg0 + t];
    const float* rb = r + (size_t)b * (CIN * NGRID);

    f32x4 acc = {0.0f, 0.0f, 0.0f, 0.0f};

    if (uni) {
        const float s     = sqrtf(-a2[0]);   // w = exp2(-(s*g - s*x)^2)
        const float sxm   = s * xmin;
        const float sstep = s * step;
        const float sx    = s * xT;
        const float* rrow = rb + (lane & 15) * NGRID + wk0 + kb * 8;

        #pragma unroll
        for (int kk = 0; kk < KSTEP; ++kk) {
            const int k0 = wk0 + kk * 32;
            float4 r0 = *reinterpret_cast<const float4*>(rrow + kk * 32);
            float4 r1 = *reinterpret_cast<const float4*>(rrow + kk * 32 + 4);
            ABfrag A;
            A.s2[0] = pk_bf16(r0.x, r0.y);
            A.s2[1] = pk_bf16(r0.z, r0.w);
            A.s2[2] = pk_bf16(r1.x, r1.y);
            A.s2[3] = pk_bf16(r1.z, r1.w);
            float wgt[8];
            #pragma unroll
            for (int j = 0; j < 8; ++j) {
                float gi = (float)(k0 + kb * 8 + j);
                float d  = __builtin_fmaf(sstep, gi, sxm) - sx;
                wgt[j] = fexp2(-(d * d));
            }
            ABfrag Bf;
            #pragma unroll
            for (int p = 0; p < 4; ++p)
                Bf.s2[p] = pk_bf16(wgt[2 * p], wgt[2 * p + 1]);
            acc = __builtin_amdgcn_mfma_f32_16x16x32_bf16(A.v, Bf.v, acc, 0, 0, 0);
        }
    } else {
        // generic per-channel-sigma fallback (f32 VALU), same C-frag layout
        #pragma unroll 1
        for (int k = 0; k < KSL; ++k) {
            float g  = xmin + step * (float)(wk0 + k);
            float d  = g - xT;
            float d2 = d * d;
            #pragma unroll
            for (int reg = 0; reg < 4; ++reg) {
                int c = kb * 4 + reg;
                acc[reg] += rb[c * NGRID + wk0 + k] * fexp2(a2[c] * d2);
            }
        }
    }

    // ---- write C fragments; cross-wave K reduction ----
    #pragma unroll
    for (int reg = 0; reg < 4; ++reg)
        part[wv][kb * 4 + reg][t] = acc[reg];
    __syncthreads();

    if (tid < CIN * NT) {                 // 256 threads: one (c,t) each
        const int c  = tid >> 4;
        const int tt = tid & 15;
        float z = 0.0f;
        #pragma unroll
        for (int w2 = 0; w2 < NW; ++w2) z += part[w2][c][tt];
        zbuf[c][tt] = z;
    }
    __syncthreads();

    // ---- epilogue: 512 threads, one (t, cout) each ----
    if (tid < NT * COUT) {
        const int tt = tid >> 5;
        const int co = tid & 31;
        float o = bias[co];
        #pragma unroll
        for (int c = 0; c < CIN; ++c)
            o = __builtin_fmaf(zbuf[c][tt], W[c * COUT + co], o);
        out[((size_t)b * NOUT + tg0 + tt) * COUT + co] = o;
    }
}

extern "C" void kernel_launch(void* const* d_in, const int* in_sizes, int n_in,
                              void* d_out, int out_size, void* d_ws, size_t ws_size,
                              hipStream_t stream) {
    const float* r  = (const float*)d_in[0];  // (4,16,2048)
    const float* xc = (const float*)d_in[1];  // (4,256,1)
    // d_in[2] = y_context — unused by the reference
    const float* xt = (const float*)d_in[3];  // (4,1024,1)
    const float* sg = (const float*)d_in[4];  // (16)
    const float* W  = (const float*)d_in[5];  // (16,32)
    const float* bs = (const float*)d_in[6];  // (32)
    float* out = (float*)d_out;               // (4,1024,32) f32

    conv_decoder_mfma<<<NBLK, 1024, 0, stream>>>(r, xc, xt, sg, W, bs, out);
}